// Round 8
// baseline (493.562 us; speedup 1.0000x reference)
//
#include <hip/hip_runtime.h>

#define N_NODES 50000
#define E_EDGES 262144

typedef __attribute__((ext_vector_type(8))) short bf16x8;
typedef __attribute__((ext_vector_type(4))) float f32x4;

union V16 { uint4 u; bf16x8 h; };

__device__ __forceinline__ unsigned rne_pack(float a, float b) {
  unsigned ua = __float_as_uint(a); ua += 0x7fffu + ((ua >> 16) & 1u);
  unsigned ub = __float_as_uint(b); ub += 0x7fffu + ((ub >> 16) & 1u);
  return (ua >> 16) | (ub & 0xffff0000u);
}
__device__ __forceinline__ float bflo(unsigned u) { return __uint_as_float(u << 16); }
__device__ __forceinline__ float bfhi(unsigned u) { return __uint_as_float(u & 0xffff0000u); }
// (bits(a)>>16) | (bits(b)&0xffff0000) in one v_perm_b32
__device__ __forceinline__ unsigned perm_pack(float a, float b) {
  return __builtin_amdgcn_perm(__float_as_uint(b), __float_as_uint(a), 0x07060302u);
}
__device__ __forceinline__ void async_gather16(const void* gptr, void* lptr) {
  __builtin_amdgcn_global_load_lds(
      (const __attribute__((address_space(1))) void*)gptr,
      (__attribute__((address_space(3))) void*)lptr, 16, 0, 0);
}

// ---- prep: node_repr fp32 -> bf16 (RNE) ----
__global__ void cvt_node_kernel(const float* __restrict__ x, unsigned short* __restrict__ y) {
  int i = (blockIdx.x * 256 + threadIdx.x) * 8;
  float4 f0 = *(const float4*)(x + i);
  float4 f1 = *(const float4*)(x + i + 4);
  uint4 o;
  o.x = rne_pack(f0.x, f0.y);
  o.y = rne_pack(f0.z, f0.w);
  o.z = rne_pack(f1.x, f1.y);
  o.w = rne_pack(f1.z, f1.w);
  *(uint4*)(y + i) = o;
}

// ---- prep: W1 (1024x512 row-major in->out) -> W1pp2 bf16, 16-B units laid out
// [step(8)][sq=s*4+quad(16)][col(512)], unit = W1[k0..k0+8)[col], k0=s*256+step*32+quad*8
__global__ void prep_w1pp2_kernel(const float* __restrict__ w1, unsigned short* __restrict__ w1pp2) {
  int t = blockIdx.x * 256 + threadIdx.x;  // 65536 units
  int step = t >> 13;
  int rem = t & 8191;
  int sq = rem >> 9;
  int col = rem & 511;
  int s = sq >> 2, qd = sq & 3;
  int k0 = s * 256 + step * 32 + qd * 8;
  float f[8];
#pragma unroll
  for (int i = 0; i < 8; ++i) f[i] = w1[(size_t)(k0 + i) * 512 + col];
  uint4 o;
  o.x = rne_pack(f[0], f[1]);
  o.y = rne_pack(f[2], f[3]);
  o.z = rne_pack(f[4], f[5]);
  o.w = rne_pack(f[6], f[7]);
  *(uint4*)(w1pp2 + (size_t)t * 8) = o;
}

// ---- prep: out[e][c] = b2[c] ----
__global__ void init_out_kernel(float* __restrict__ out, const float* __restrict__ b2) {
  int i = blockIdx.x * 256 + threadIdx.x;
  float2 v; v.x = b2[0]; v.y = b2[1];
  *(float2*)(out + (size_t)i * 2) = v;
}

// ---- main fused kernel: block = 256 edges x 64 cols; 4 waves share one B col-slice (L1);
//      A via LDS dbuf (1 barrier/step); B loads FIFO-head, A-gathers FIFO-tail ----
__global__ __launch_bounds__(256, 2) void edge_mlp_kernel(
    const unsigned short* __restrict__ nodeb,  // [50000][256] bf16
    const unsigned short* __restrict__ w1pp2,  // repacked W1 (see prep)
    const int* __restrict__ src,
    const int* __restrict__ dst,
    const float* __restrict__ b1,
    const float* __restrict__ w2,   // [512][2] fp32
    float* __restrict__ out) {      // [E][2] fp32, pre-init with b2
  // A buffers: buf p at [p*32K, +32K): hi 16K | hj 16K
  __shared__ char smem[65536];

  const int tid = threadIdx.x;
  const int wid = tid >> 6;
  const int lane = tid & 63;
  const int quad = lane >> 4;
  const int l16 = lane & 15;
  const int bx = blockIdx.x;
  // swizzle: XCD c = bx&7; the 8 n-siblings of one m-tile are 8 consecutive t on one XCD
  const int xc = bx & 7;
  const int t2 = bx >> 3;
  const int n_idx = t2 & 7;                    // 0..7 (64-col slices)
  const int m_idx = (t2 >> 3) * 8 + xc;        // 0..1023 (256-edge tiles)
  const int row0 = m_idx * 256;
  const int wrow0 = row0 + wid * 64;
  const int n0 = n_idx * 64;

  const char* nodeB = (const char*)nodeb;
  const char* w1B = (const char*)w1pp2;

  // ---- A stager state: hi-region slot u = e*4+qp (16B), e=u>>2; wave wid, call c covers
  // u in [(wid*4+c)*64, +64): e = (wid*4+c)*16 + (lane>>2), qp = lane&3, global quad = qp^((lane>>3)&3)
  unsigned oi[4], oj[4];
#pragma unroll
  for (int c = 0; c < 4; ++c) {
    int e = (wid * 4 + c) * 16 + (lane >> 2);
    unsigned qg = (unsigned)(((lane & 3) ^ ((lane >> 3) & 3)) << 4);
    oi[c] = ((unsigned)src[row0 + e] << 9) + qg;
    oj[c] = ((unsigned)dst[row0 + e] << 9) + qg;
  }
  // ---- B offsets (all 4 waves identical -> L1 dedup): (s*4+quad)*8192 + (n0+l16)*16
  unsigned bOff[4];
#pragma unroll
  for (int s = 0; s < 4; ++s)
    bOff[s] = (unsigned)((s * 4 + quad) * 8192 + (n0 + l16) * 16);
  const char* w1s = w1B;  // stepped by 131072 per step (SGPR add)

  // ---- A reader base: e = wid*64 + mt*16 + l16; addr = e*64 + (quad^((l16>>1)&3))*16
  const unsigned aR = (unsigned)((wid * 64 + l16) * 64 + ((quad ^ ((l16 >> 1) & 3)) << 4));

  f32x4 acc[4][4];
#pragma unroll
  for (int mt = 0; mt < 4; ++mt)
#pragma unroll
    for (int nt = 0; nt < 4; ++nt)
      acc[mt][nt] = (f32x4){0.f, 0.f, 0.f, 0.f};

  // ---- prologue: stage A(0) into buf0 ----
#pragma unroll
  for (int c = 0; c < 4; ++c) {
    async_gather16(nodeB + oi[c], smem + (wid * 4 + c) * 1024);
    async_gather16(nodeB + oj[c], smem + 16384 + (wid * 4 + c) * 1024);
  }
  __syncthreads();

  int p = 0;
#pragma unroll 1
  for (int step = 0; step < 8; ++step) {
    const char* Acur = smem + (p << 15);
    // 1) B(t) loads first — vm FIFO head; waits on B never chain behind random gathers
    V16 bf[4][4];
#pragma unroll
    for (int s = 0; s < 4; ++s)
#pragma unroll
      for (int nt = 0; nt < 4; ++nt)
        bf[s][nt].u = *(const uint4*)(w1s + bOff[s] + nt * 256);
    // 2) A(t+1) gathers — vm FIFO tail; drained by end-of-step barrier (full-step flight)
    if (step < 7) {
      const unsigned aoN = (unsigned)(step + 1) * 64u;
      char* Aalt = smem + ((p ^ 1) << 15);
#pragma unroll
      for (int c = 0; c < 4; ++c) {
        async_gather16(nodeB + (oi[c] + aoN), Aalt + (wid * 4 + c) * 1024);
        async_gather16(nodeB + (oj[c] + aoN), Aalt + 16384 + (wid * 4 + c) * 1024);
      }
    }
    // 3) A fragments from LDS
    V16 hi[4], hj[4];
#pragma unroll
    for (int mt = 0; mt < 4; ++mt) {
      hi[mt].u = *(const uint4*)(Acur + aR + mt * 1024);
      hj[mt].u = *(const uint4*)(Acur + 16384 + aR + mt * 1024);
    }
    // 4) MFMA s=0 (hi), s=1 (hj) — consumes FIFO-oldest B first
#pragma unroll
    for (int sl = 0; sl < 2; ++sl) {
#pragma unroll
      for (int mt = 0; mt < 4; ++mt) {
        bf16x8 af = (sl == 0) ? hi[mt].h : hj[mt].h;
#pragma unroll
        for (int nt = 0; nt < 4; ++nt)
          acc[mt][nt] = __builtin_amdgcn_mfma_f32_16x16x32_bf16(af, bf[sl][nt].h, acc[mt][nt], 0, 0, 0);
      }
    }
    // 5) build a2/a3 JIT per mt, MFMA s=2,3
#pragma unroll
    for (int mt = 0; mt < 4; ++mt) {
      const unsigned hw[4] = {hi[mt].u.x, hi[mt].u.y, hi[mt].u.z, hi[mt].u.w};
      const unsigned jw[4] = {hj[mt].u.x, hj[mt].u.y, hj[mt].u.z, hj[mt].u.w};
      unsigned d[4], pr[4];
#pragma unroll
      for (int w = 0; w < 4; ++w) {
        float i0 = bflo(hw[w]), i1 = bfhi(hw[w]);
        float j0 = bflo(jw[w]), j1 = bfhi(jw[w]);
        d[w] = perm_pack(i0 - j0, i1 - j1) & 0x7fff7fffu;
        pr[w] = perm_pack(i0 * j0, i1 * j1);
      }
      V16 a2, a3;
      a2.u = make_uint4(d[0], d[1], d[2], d[3]);
      a3.u = make_uint4(pr[0], pr[1], pr[2], pr[3]);
#pragma unroll
      for (int nt = 0; nt < 4; ++nt)
        acc[mt][nt] = __builtin_amdgcn_mfma_f32_16x16x32_bf16(a2.h, bf[2][nt].h, acc[mt][nt], 0, 0, 0);
#pragma unroll
      for (int nt = 0; nt < 4; ++nt)
        acc[mt][nt] = __builtin_amdgcn_mfma_f32_16x16x32_bf16(a3.h, bf[3][nt].h, acc[mt][nt], 0, 0, 0);
    }
    __syncthreads();  // drains A(t+1) gathers; all LDS reads of Acur done block-wide
    w1s += 131072;
    p ^= 1;
  }

  // ---- epilogue: bias + ReLU + W2, 16-lane shuffle reduce, atomic out ----
#pragma unroll
  for (int mt = 0; mt < 4; ++mt) {
    float pc0[4] = {0.f, 0.f, 0.f, 0.f};
    float pc1[4] = {0.f, 0.f, 0.f, 0.f};
#pragma unroll
    for (int nt = 0; nt < 4; ++nt) {
      int gc = n0 + nt * 16 + l16;
      float b1v = b1[gc];
      float w20 = w2[gc * 2 + 0];
      float w21 = w2[gc * 2 + 1];
#pragma unroll
      for (int r = 0; r < 4; ++r) {
        float v = fmaxf(acc[mt][nt][r] + b1v, 0.f);
        pc0[r] = fmaf(v, w20, pc0[r]);
        pc1[r] = fmaf(v, w21, pc1[r]);
      }
    }
#pragma unroll
    for (int r = 0; r < 4; ++r) {
      float s0 = pc0[r], s1 = pc1[r];
#pragma unroll
      for (int off = 1; off < 16; off <<= 1) {
        s0 += __shfl_xor(s0, off);
        s1 += __shfl_xor(s1, off);
      }
      int e = wrow0 + mt * 16 + quad * 4 + r;  // C/D: row = quad*4 + r
      if (l16 == 0) unsafeAtomicAdd(&out[(size_t)e * 2 + 0], s0);
      if (l16 == 1) unsafeAtomicAdd(&out[(size_t)e * 2 + 1], s1);
    }
  }
}

extern "C" void kernel_launch(void* const* d_in, const int* in_sizes, int n_in,
                              void* d_out, int out_size, void* d_ws, size_t ws_size,
                              hipStream_t stream) {
  const float* node = (const float*)d_in[0];
  const int* src = (const int*)d_in[1];
  const int* dst = (const int*)d_in[2];
  const float* W1 = (const float*)d_in[3];
  const float* b1 = (const float*)d_in[4];
  const float* W2 = (const float*)d_in[5];
  const float* b2 = (const float*)d_in[6];
  float* out = (float*)d_out;

  unsigned short* nodeb = (unsigned short*)d_ws;                      // 25,600,000 B
  unsigned short* w1pp2 = (unsigned short*)((char*)d_ws + 25600000);  // 1,048,576 B

  cvt_node_kernel<<<6250, 256, 0, stream>>>(node, nodeb);
  prep_w1pp2_kernel<<<256, 256, 0, stream>>>(W1, w1pp2);
  init_out_kernel<<<1024, 256, 0, stream>>>(out, b2);
  edge_mlp_kernel<<<8192, 256, 0, stream>>>(nodeb, w1pp2, src, dst, b1, W2, out);
}

// Round 9
// 477.102 us; speedup vs baseline: 1.0345x; 1.0345x over previous
//
#include <hip/hip_runtime.h>

#define N_NODES 50000
#define E_EDGES 262144

typedef __attribute__((ext_vector_type(8))) short bf16x8;
typedef __attribute__((ext_vector_type(4))) float f32x4;

union V16 { uint4 u; bf16x8 h; };

__device__ __forceinline__ unsigned rne_pack(float a, float b) {
  unsigned ua = __float_as_uint(a); ua += 0x7fffu + ((ua >> 16) & 1u);
  unsigned ub = __float_as_uint(b); ub += 0x7fffu + ((ub >> 16) & 1u);
  return (ua >> 16) | (ub & 0xffff0000u);
}
__device__ __forceinline__ float bflo(unsigned u) { return __uint_as_float(u << 16); }
__device__ __forceinline__ float bfhi(unsigned u) { return __uint_as_float(u & 0xffff0000u); }
// (bits(a)>>16) | (bits(b)&0xffff0000) in one v_perm_b32
__device__ __forceinline__ unsigned perm_pack(float a, float b) {
  return __builtin_amdgcn_perm(__float_as_uint(b), __float_as_uint(a), 0x07060302u);
}
__device__ __forceinline__ void async_gather16(const void* gptr, void* lptr) {
  __builtin_amdgcn_global_load_lds(
      (const __attribute__((address_space(1))) void*)gptr,
      (__attribute__((address_space(3))) void*)lptr, 16, 0, 0);
}

// ---- prep: node_repr fp32 -> bf16 (RNE) ----
__global__ void cvt_node_kernel(const float* __restrict__ x, unsigned short* __restrict__ y) {
  int i = (blockIdx.x * 256 + threadIdx.x) * 8;
  float4 f0 = *(const float4*)(x + i);
  float4 f1 = *(const float4*)(x + i + 4);
  uint4 o;
  o.x = rne_pack(f0.x, f0.y);
  o.y = rne_pack(f0.z, f0.w);
  o.z = rne_pack(f1.x, f1.y);
  o.w = rne_pack(f1.z, f1.w);
  *(uint4*)(y + i) = o;
}

// ---- prep: W1 (1024x512 row-major in->out) -> W1pp2 bf16, 16-B units laid out
// [step(8)][sq=s*4+quad(16)][col(512)], unit = W1[k0..k0+8)[col], k0=s*256+step*32+quad*8
__global__ void prep_w1pp2_kernel(const float* __restrict__ w1, unsigned short* __restrict__ w1pp2) {
  int t = blockIdx.x * 256 + threadIdx.x;  // 65536 units
  int step = t >> 13;
  int rem = t & 8191;
  int sq = rem >> 9;
  int col = rem & 511;
  int s = sq >> 2, qd = sq & 3;
  int k0 = s * 256 + step * 32 + qd * 8;
  float f[8];
#pragma unroll
  for (int i = 0; i < 8; ++i) f[i] = w1[(size_t)(k0 + i) * 512 + col];
  uint4 o;
  o.x = rne_pack(f[0], f[1]);
  o.y = rne_pack(f[2], f[3]);
  o.z = rne_pack(f[4], f[5]);
  o.w = rne_pack(f[6], f[7]);
  *(uint4*)(w1pp2 + (size_t)t * 8) = o;
}

// ---- prep: out[e][c] = b2[c] ----
__global__ void init_out_kernel(float* __restrict__ out, const float* __restrict__ b2) {
  int i = blockIdx.x * 256 + threadIdx.x;
  float2 v; v.x = b2[0]; v.y = b2[1];
  *(float2*)(out + (size_t)i * 2) = v;
}

// ---- main fused kernel: 128x128 tile, 32KB LDS A-dbuf, B FIFO-head, 3 blocks/CU target ----
__global__ __launch_bounds__(256, 3) void edge_mlp_kernel(
    const unsigned short* __restrict__ nodeb,  // [50000][256] bf16
    const unsigned short* __restrict__ w1pp2,  // repacked W1 (see prep)
    const int* __restrict__ src,
    const int* __restrict__ dst,
    const float* __restrict__ b1,
    const float* __restrict__ w2,   // [512][2] fp32
    float* __restrict__ out) {      // [E][2] fp32, pre-init with b2
  // A buffers: buf p at [p*16K, p*16K+16K): hi 8K | hj 8K
  __shared__ char smem[32768];

  const int tid = threadIdx.x;
  const int wid = tid >> 6;
  const int lane = tid & 63;
  const int quad = lane >> 4;
  const int l16 = lane & 15;
  const int bx = blockIdx.x;
  const int m_idx = ((bx >> 5) << 3) + (bx & 7);  // sibling n-blocks -> same XCD
  const int n_idx = (bx >> 3) & 3;
  const int wave_m = wid >> 1;
  const int wave_n = wid & 1;
  const int row0 = m_idx * 128;
  const int wrow0 = row0 + wave_m * 64;
  const int n0 = n_idx * 128 + wave_n * 64;

  const char* nodeB = (const char*)nodeb;
  const char* w1B = (const char*)w1pp2;

  // ---- A stager state: unit u=c*256+tid -> e=u>>2, LDS slot holds global quad (tid&3)^((tid>>3)&3)
  const int eh = tid >> 2;
  const unsigned qsw = (unsigned)(((tid & 3) ^ ((tid >> 3) & 3)) << 4);
  const unsigned oi0 = ((unsigned)src[row0 + eh] << 9) + qsw;
  const unsigned oi1 = ((unsigned)src[row0 + 64 + eh] << 9) + qsw;
  const unsigned oj0 = ((unsigned)dst[row0 + eh] << 9) + qsw;
  const unsigned oj1 = ((unsigned)dst[row0 + 64 + eh] << 9) + qsw;
  const unsigned sdst = (unsigned)(wid * 1024);  // wave-uniform LDS dest offset

  // ---- B register-load offsets: (s*4+quad)*8192 + (n0 + l16)*16  (+ step*131072)
  unsigned bOff[4];
#pragma unroll
  for (int s = 0; s < 4; ++s)
    bOff[s] = (unsigned)((s * 4 + quad) * 8192 + (n0 + l16) * 16);
  const char* w1s = w1B;  // stepped by 131072 per step

  // ---- A reader base ----
  const unsigned aR = (unsigned)((wave_m * 64 + l16) * 64 + ((quad ^ ((l16 >> 1) & 3)) << 4));

  f32x4 acc[4][4];
#pragma unroll
  for (int mt = 0; mt < 4; ++mt)
#pragma unroll
    for (int nt = 0; nt < 4; ++nt)
      acc[mt][nt] = (f32x4){0.f, 0.f, 0.f, 0.f};

  // ---- prologue: stage A(0) into buf0 ----
  async_gather16(nodeB + oi0, smem + sdst);
  async_gather16(nodeB + oi1, smem + 4096 + sdst);
  async_gather16(nodeB + oj0, smem + 8192 + sdst);
  async_gather16(nodeB + oj1, smem + 12288 + sdst);
  __syncthreads();

  int p = 0;
#pragma unroll 1
  for (int step = 0; step < 8; ++step) {
    const char* Acur = smem + (p << 14);
    // 1) B(t) loads — vm FIFO head; B-consumption waits don't chain behind gathers
    V16 bf[4][4];
#pragma unroll
    for (int s = 0; s < 4; ++s)
#pragma unroll
      for (int nt = 0; nt < 4; ++nt)
        bf[s][nt].u = *(const uint4*)(w1s + bOff[s] + nt * 256);
    // 2) A(t+1) gathers — vm FIFO tail; full-step flight before barrier drain
    if (step < 7) {
      const unsigned aoN = (unsigned)(step + 1) * 64u;
      char* Aalt = smem + ((p ^ 1) << 14);
      async_gather16(nodeB + (oi0 + aoN), Aalt + sdst);
      async_gather16(nodeB + (oi1 + aoN), Aalt + 4096 + sdst);
      async_gather16(nodeB + (oj0 + aoN), Aalt + 8192 + sdst);
      async_gather16(nodeB + (oj1 + aoN), Aalt + 12288 + sdst);
    }
    // 3) A fragments from LDS
    V16 hi[4], hj[4];
#pragma unroll
    for (int mt = 0; mt < 4; ++mt) {
      hi[mt].u = *(const uint4*)(Acur + aR + mt * 1024);
      hj[mt].u = *(const uint4*)(Acur + 8192 + aR + mt * 1024);
    }
    // 4) MFMA s=0 (hi), s=1 (hj)
#pragma unroll
    for (int sl = 0; sl < 2; ++sl) {
#pragma unroll
      for (int mt = 0; mt < 4; ++mt) {
        bf16x8 af = (sl == 0) ? hi[mt].h : hj[mt].h;
#pragma unroll
        for (int nt = 0; nt < 4; ++nt)
          acc[mt][nt] = __builtin_amdgcn_mfma_f32_16x16x32_bf16(af, bf[sl][nt].h, acc[mt][nt], 0, 0, 0);
      }
    }
    // 5) build a2/a3 JIT per mt, MFMA s=2,3
#pragma unroll
    for (int mt = 0; mt < 4; ++mt) {
      const unsigned hw[4] = {hi[mt].u.x, hi[mt].u.y, hi[mt].u.z, hi[mt].u.w};
      const unsigned jw[4] = {hj[mt].u.x, hj[mt].u.y, hj[mt].u.z, hj[mt].u.w};
      unsigned d[4], pr[4];
#pragma unroll
      for (int w = 0; w < 4; ++w) {
        float i0 = bflo(hw[w]), i1 = bfhi(hw[w]);
        float j0 = bflo(jw[w]), j1 = bfhi(jw[w]);
        d[w] = perm_pack(i0 - j0, i1 - j1) & 0x7fff7fffu;
        pr[w] = perm_pack(i0 * j0, i1 * j1);
      }
      V16 a2, a3;
      a2.u = make_uint4(d[0], d[1], d[2], d[3]);
      a3.u = make_uint4(pr[0], pr[1], pr[2], pr[3]);
#pragma unroll
      for (int nt = 0; nt < 4; ++nt)
        acc[mt][nt] = __builtin_amdgcn_mfma_f32_16x16x32_bf16(a2.h, bf[2][nt].h, acc[mt][nt], 0, 0, 0);
#pragma unroll
      for (int nt = 0; nt < 4; ++nt)
        acc[mt][nt] = __builtin_amdgcn_mfma_f32_16x16x32_bf16(a3.h, bf[3][nt].h, acc[mt][nt], 0, 0, 0);
    }
    __syncthreads();  // drains A(t+1) gathers; all LDS reads of Acur done block-wide
    w1s += 131072;
    p ^= 1;
  }

  // ---- epilogue: bias + ReLU + W2, 16-lane shuffle reduce, atomic out ----
#pragma unroll
  for (int mt = 0; mt < 4; ++mt) {
    float pc0[4] = {0.f, 0.f, 0.f, 0.f};
    float pc1[4] = {0.f, 0.f, 0.f, 0.f};
#pragma unroll
    for (int nt = 0; nt < 4; ++nt) {
      int gc = n0 + nt * 16 + l16;
      float b1v = b1[gc];
      float w20 = w2[gc * 2 + 0];
      float w21 = w2[gc * 2 + 1];
#pragma unroll
      for (int r = 0; r < 4; ++r) {
        float v = fmaxf(acc[mt][nt][r] + b1v, 0.f);
        pc0[r] = fmaf(v, w20, pc0[r]);
        pc1[r] = fmaf(v, w21, pc1[r]);
      }
    }
#pragma unroll
    for (int r = 0; r < 4; ++r) {
      float s0 = pc0[r], s1 = pc1[r];
#pragma unroll
      for (int off = 1; off < 16; off <<= 1) {
        s0 += __shfl_xor(s0, off);
        s1 += __shfl_xor(s1, off);
      }
      int e = wrow0 + mt * 16 + quad * 4 + r;  // C/D: row = quad*4 + r
      if (l16 == 0) unsafeAtomicAdd(&out[(size_t)e * 2 + 0], s0);
      if (l16 == 1) unsafeAtomicAdd(&out[(size_t)e * 2 + 1], s1);
    }
  }
}

extern "C" void kernel_launch(void* const* d_in, const int* in_sizes, int n_in,
                              void* d_out, int out_size, void* d_ws, size_t ws_size,
                              hipStream_t stream) {
  const float* node = (const float*)d_in[0];
  const int* src = (const int*)d_in[1];
  const int* dst = (const int*)d_in[2];
  const float* W1 = (const float*)d_in[3];
  const float* b1 = (const float*)d_in[4];
  const float* W2 = (const float*)d_in[5];
  const float* b2 = (const float*)d_in[6];
  float* out = (float*)d_out;

  unsigned short* nodeb = (unsigned short*)d_ws;                      // 25,600,000 B
  unsigned short* w1pp2 = (unsigned short*)((char*)d_ws + 25600000);  // 1,048,576 B

  cvt_node_kernel<<<6250, 256, 0, stream>>>(node, nodeb);
  prep_w1pp2_kernel<<<256, 256, 0, stream>>>(W1, w1pp2);
  init_out_kernel<<<1024, 256, 0, stream>>>(out, b2);
  edge_mlp_kernel<<<8192, 256, 0, stream>>>(nodeb, w1pp2, src, dst, b1, W2, out);
}

// Round 10
// 411.676 us; speedup vs baseline: 1.1989x; 1.1589x over previous
//
#include <hip/hip_runtime.h>

#define N_NODES 50000
#define E_EDGES 262144

typedef __attribute__((ext_vector_type(8))) short bf16x8;
typedef __attribute__((ext_vector_type(4))) float f32x4;

union V16 { uint4 u; bf16x8 h; };

__device__ __forceinline__ unsigned rne_pack(float a, float b) {
  unsigned ua = __float_as_uint(a); ua += 0x7fffu + ((ua >> 16) & 1u);
  unsigned ub = __float_as_uint(b); ub += 0x7fffu + ((ub >> 16) & 1u);
  return (ua >> 16) | (ub & 0xffff0000u);
}
__device__ __forceinline__ float bflo(unsigned u) { return __uint_as_float(u << 16); }
__device__ __forceinline__ float bfhi(unsigned u) { return __uint_as_float(u & 0xffff0000u); }
// (bits(a)>>16) | (bits(b)&0xffff0000) in one v_perm_b32
__device__ __forceinline__ unsigned perm_pack(float a, float b) {
  return __builtin_amdgcn_perm(__float_as_uint(b), __float_as_uint(a), 0x07060302u);
}
__device__ __forceinline__ void async_gather16(const void* gptr, void* lptr) {
  __builtin_amdgcn_global_load_lds(
      (const __attribute__((address_space(1))) void*)gptr,
      (__attribute__((address_space(3))) void*)lptr, 16, 0, 0);
}

// ---- prep: node_repr fp32 -> bf16 (RNE) ----
__global__ void cvt_node_kernel(const float* __restrict__ x, unsigned short* __restrict__ y) {
  int i = (blockIdx.x * 256 + threadIdx.x) * 8;
  float4 f0 = *(const float4*)(x + i);
  float4 f1 = *(const float4*)(x + i + 4);
  uint4 o;
  o.x = rne_pack(f0.x, f0.y);
  o.y = rne_pack(f0.z, f0.w);
  o.z = rne_pack(f1.x, f1.y);
  o.w = rne_pack(f1.z, f1.w);
  *(uint4*)(y + i) = o;
}

// ---- prep: W1 (1024x512 row-major in->out) -> W1pp2 bf16, 16-B units laid out
// [step(8)][sq=s*4+quad(16)][col(512)], unit = W1[k0..k0+8)[col], k0=s*256+step*32+quad*8
__global__ void prep_w1pp2_kernel(const float* __restrict__ w1, unsigned short* __restrict__ w1pp2) {
  int t = blockIdx.x * 256 + threadIdx.x;  // 65536 units
  int step = t >> 13;
  int rem = t & 8191;
  int sq = rem >> 9;
  int col = rem & 511;
  int s = sq >> 2, qd = sq & 3;
  int k0 = s * 256 + step * 32 + qd * 8;
  float f[8];
#pragma unroll
  for (int i = 0; i < 8; ++i) f[i] = w1[(size_t)(k0 + i) * 512 + col];
  uint4 o;
  o.x = rne_pack(f[0], f[1]);
  o.y = rne_pack(f[2], f[3]);
  o.z = rne_pack(f[4], f[5]);
  o.w = rne_pack(f[6], f[7]);
  *(uint4*)(w1pp2 + (size_t)t * 8) = o;
}

// ---- prep: out[e][c] = b2[c] ----
__global__ void init_out_kernel(float* __restrict__ out, const float* __restrict__ b2) {
  int i = blockIdx.x * 256 + threadIdx.x;
  float2 v; v.x = b2[0]; v.y = b2[1];
  *(float2*)(out + (size_t)i * 2) = v;
}

// ---- main fused kernel: block = 64 edges x 256 cols; ALL of A staged once (64 KB LDS),
//      ONE barrier total; K-loop is barrier-free, B streamed with fine-grained vmcnt ----
__global__ __launch_bounds__(256) void edge_mlp_kernel(
    const unsigned short* __restrict__ nodeb,  // [50000][256] bf16
    const unsigned short* __restrict__ w1pp2,  // repacked W1 (see prep)
    const int* __restrict__ src,
    const int* __restrict__ dst,
    const float* __restrict__ b1,
    const float* __restrict__ w2,   // [512][2] fp32
    float* __restrict__ out) {      // [E][2] fp32, pre-init with b2
  // hi: [0,32K) — 64 edges x 512 B; hj: [32K,64K)
  // 16-B unit slot for (e, st, q): e*32 + ((st*4+q) ^ (e&7))
  __shared__ char smem[65536];

  const int tid = threadIdx.x;
  const int wid = tid >> 6;
  const int lane = tid & 63;
  const int quad = lane >> 4;
  const int l16 = lane & 15;
  const int bx = blockIdx.x;
  // XCD swizzle: xc = bx&7; n-siblings + neighbor m-tiles share an XCD
  const int xc = bx & 7;
  const int t2 = bx >> 3;
  const int n_half = t2 & 1;                 // 0..1 (256-col halves)
  const int m_idx = (t2 >> 1) * 8 + xc;      // 0..4095 (64-edge tiles)
  const int row0 = m_idx * 64;
  const int n0 = n_half * 256 + wid * 64;

  const char* nodeB = (const char*)nodeb;
  const char* w1B = (const char*)w1pp2;

  // ---- B register-load offsets: (s*4+quad)*8192 + (n0+l16)*16 (+ step*131072) ----
  unsigned bOff[4];
#pragma unroll
  for (int s = 0; s < 4; ++s)
    bOff[s] = (unsigned)((s * 4 + quad) * 8192 + (n0 + l16) * 16);
  const char* w1s = w1B;

  // ---- A reader base: byte = (mt*16+l16)*512 + (((st*4+q)^(l16&7))<<4) ----
  const unsigned aXor = (unsigned)(l16 & 7);
  const unsigned aBase = (unsigned)(l16 * 512);

  f32x4 acc[4][4];
#pragma unroll
  for (int mt = 0; mt < 4; ++mt)
#pragma unroll
    for (int nt = 0; nt < 4; ++nt)
      acc[mt][nt] = (f32x4){0.f, 0.f, 0.f, 0.f};

  // ---- prologue: stage ALL of A (hi+hj, 64 edges x 512 B each region) ----
  // call c stages slots v = c*256+tid; e = v>>5 = c*8 + (tid>>5); w = (tid&31)^(e&7)
  {
    const int eh = tid >> 5;
    const unsigned wsw = (unsigned)(((tid & 31) ^ (eh & 7)) << 4);  // e&7 == eh&7 since c*8 aligned
#pragma unroll
    for (int c = 0; c < 8; ++c) {
      int e = c * 8 + eh;
      unsigned so = ((unsigned)src[row0 + e] << 9) + wsw;
      unsigned do_ = ((unsigned)dst[row0 + e] << 9) + wsw;
      async_gather16(nodeB + so, smem + c * 4096 + wid * 1024);
      async_gather16(nodeB + do_, smem + 32768 + c * 4096 + wid * 1024);
    }
  }
  __syncthreads();  // the ONLY barrier

#pragma unroll 2
  for (int step = 0; step < 8; ++step) {
    // B(t) loads — compiler emits fine-grained vmcnt; with unroll-2, B(t+1) overlaps MFMAs
    V16 bf[4][4];
#pragma unroll
    for (int s = 0; s < 4; ++s)
#pragma unroll
      for (int nt = 0; nt < 4; ++nt)
        bf[s][nt].u = *(const uint4*)(w1s + bOff[s] + nt * 256);
    // A fragments from LDS (read-only, no sync needed)
    const unsigned stq = (unsigned)(step * 4 + quad);
    V16 hi[4], hj[4];
#pragma unroll
    for (int mt = 0; mt < 4; ++mt) {
      unsigned ao = (unsigned)(mt * 16 * 512) + aBase + ((stq ^ aXor) << 4);
      hi[mt].u = *(const uint4*)(smem + ao);
      hj[mt].u = *(const uint4*)(smem + 32768 + ao);
    }
    // MFMA s=0 (hi), s=1 (hj)
#pragma unroll
    for (int sl = 0; sl < 2; ++sl) {
#pragma unroll
      for (int mt = 0; mt < 4; ++mt) {
        bf16x8 af = (sl == 0) ? hi[mt].h : hj[mt].h;
#pragma unroll
        for (int nt = 0; nt < 4; ++nt)
          acc[mt][nt] = __builtin_amdgcn_mfma_f32_16x16x32_bf16(af, bf[sl][nt].h, acc[mt][nt], 0, 0, 0);
      }
    }
    // build a2/a3 JIT per mt, MFMA s=2,3
#pragma unroll
    for (int mt = 0; mt < 4; ++mt) {
      const unsigned hw[4] = {hi[mt].u.x, hi[mt].u.y, hi[mt].u.z, hi[mt].u.w};
      const unsigned jw[4] = {hj[mt].u.x, hj[mt].u.y, hj[mt].u.z, hj[mt].u.w};
      unsigned d[4], pr[4];
#pragma unroll
      for (int w = 0; w < 4; ++w) {
        float i0 = bflo(hw[w]), i1 = bfhi(hw[w]);
        float j0 = bflo(jw[w]), j1 = bfhi(jw[w]);
        d[w] = perm_pack(i0 - j0, i1 - j1) & 0x7fff7fffu;
        pr[w] = perm_pack(i0 * j0, i1 * j1);
      }
      V16 a2, a3;
      a2.u = make_uint4(d[0], d[1], d[2], d[3]);
      a3.u = make_uint4(pr[0], pr[1], pr[2], pr[3]);
#pragma unroll
      for (int nt = 0; nt < 4; ++nt)
        acc[mt][nt] = __builtin_amdgcn_mfma_f32_16x16x32_bf16(a2.h, bf[2][nt].h, acc[mt][nt], 0, 0, 0);
#pragma unroll
      for (int nt = 0; nt < 4; ++nt)
        acc[mt][nt] = __builtin_amdgcn_mfma_f32_16x16x32_bf16(a3.h, bf[3][nt].h, acc[mt][nt], 0, 0, 0);
    }
    w1s += 131072;
  }

  // ---- epilogue: bias + ReLU + W2, 16-lane shuffle reduce, atomic out ----
#pragma unroll
  for (int mt = 0; mt < 4; ++mt) {
    float pc0[4] = {0.f, 0.f, 0.f, 0.f};
    float pc1[4] = {0.f, 0.f, 0.f, 0.f};
#pragma unroll
    for (int nt = 0; nt < 4; ++nt) {
      int gc = n0 + nt * 16 + l16;
      float b1v = b1[gc];
      float w20 = w2[gc * 2 + 0];
      float w21 = w2[gc * 2 + 1];
#pragma unroll
      for (int r = 0; r < 4; ++r) {
        float v = fmaxf(acc[mt][nt][r] + b1v, 0.f);
        pc0[r] = fmaf(v, w20, pc0[r]);
        pc1[r] = fmaf(v, w21, pc1[r]);
      }
    }
#pragma unroll
    for (int r = 0; r < 4; ++r) {
      float s0 = pc0[r], s1 = pc1[r];
#pragma unroll
      for (int off = 1; off < 16; off <<= 1) {
        s0 += __shfl_xor(s0, off);
        s1 += __shfl_xor(s1, off);
      }
      int e = row0 + mt * 16 + quad * 4 + r;  // C/D: row = quad*4 + r
      if (l16 == 0) unsafeAtomicAdd(&out[(size_t)e * 2 + 0], s0);
      if (l16 == 1) unsafeAtomicAdd(&out[(size_t)e * 2 + 1], s1);
    }
  }
}

extern "C" void kernel_launch(void* const* d_in, const int* in_sizes, int n_in,
                              void* d_out, int out_size, void* d_ws, size_t ws_size,
                              hipStream_t stream) {
  const float* node = (const float*)d_in[0];
  const int* src = (const int*)d_in[1];
  const int* dst = (const int*)d_in[2];
  const float* W1 = (const float*)d_in[3];
  const float* b1 = (const float*)d_in[4];
  const float* W2 = (const float*)d_in[5];
  const float* b2 = (const float*)d_in[6];
  float* out = (float*)d_out;

  unsigned short* nodeb = (unsigned short*)d_ws;                      // 25,600,000 B
  unsigned short* w1pp2 = (unsigned short*)((char*)d_ws + 25600000);  // 1,048,576 B

  cvt_node_kernel<<<6250, 256, 0, stream>>>(node, nodeb);
  prep_w1pp2_kernel<<<256, 256, 0, stream>>>(W1, w1pp2);
  init_out_kernel<<<1024, 256, 0, stream>>>(out, b2);
  edge_mlp_kernel<<<8192, 256, 0, stream>>>(nodeb, w1pp2, src, dst, b1, W2, out);
}